// Round 1
// baseline (240.117 us; speedup 1.0000x reference)
//
#include <hip/hip_runtime.h>

// Submanifold-style 3x3 conv on independent 4x4x1 tiles.
// y[n,i,j] = sum_{ki,kj} x[n,i+ki-1,j+kj-1] * W[ki,kj]   (zero pad, per-tile)
// then y[n,i,j] = 0 where x[n,i,j] == 0.
// Output NCHW with C=1 is flat-identical to input NHWC layout: n*16 + i*4 + j.

__global__ __launch_bounds__(256) void subm_conv44_kernel(
    const float4* __restrict__ x4, const float* __restrict__ W,
    float4* __restrict__ out4, int n_tiles)
{
    int n = blockIdx.x * blockDim.x + threadIdx.x;
    if (n >= n_tiles) return;

    // 3x3 weight, HWIO flat (I=O=1): w[ki*3+kj]
    float w[9];
#pragma unroll
    for (int i = 0; i < 9; ++i) w[i] = W[i];   // uniform address -> cached/broadcast

    // Load the 4x4 tile as 4 float4 (64 B per thread).
    float4 r[4];
#pragma unroll
    for (int i = 0; i < 4; ++i) r[i] = x4[(size_t)n * 4 + i];

    float xin[4][4];
#pragma unroll
    for (int i = 0; i < 4; ++i) {
        xin[i][0] = r[i].x; xin[i][1] = r[i].y;
        xin[i][2] = r[i].z; xin[i][3] = r[i].w;
    }

    float y[4][4];
#pragma unroll
    for (int i = 0; i < 4; ++i) {
#pragma unroll
        for (int j = 0; j < 4; ++j) {
            float acc = 0.0f;
#pragma unroll
            for (int ki = 0; ki < 3; ++ki) {
                const int si = i + ki - 1;
                if (si < 0 || si > 3) continue;       // compile-time eliminated
#pragma unroll
                for (int kj = 0; kj < 3; ++kj) {
                    const int sj = j + kj - 1;
                    if (sj < 0 || sj > 3) continue;   // compile-time eliminated
                    acc = fmaf(xin[si][sj], w[ki * 3 + kj], acc);
                }
            }
            // Mask: output only at active (nonzero-input) sites.
            y[i][j] = (xin[i][j] != 0.0f) ? acc : 0.0f;
        }
    }

    float4 o[4];
#pragma unroll
    for (int i = 0; i < 4; ++i) {
        o[i].x = y[i][0]; o[i].y = y[i][1];
        o[i].z = y[i][2]; o[i].w = y[i][3];
    }
#pragma unroll
    for (int i = 0; i < 4; ++i) out4[(size_t)n * 4 + i] = o[i];
}

extern "C" void kernel_launch(void* const* d_in, const int* in_sizes, int n_in,
                              void* d_out, int out_size, void* d_ws, size_t ws_size,
                              hipStream_t stream) {
    const float4* x4 = (const float4*)d_in[0];
    const float*  W  = (const float*)d_in[1];
    float4* out4     = (float4*)d_out;

    const int n_tiles = in_sizes[0] / 16;          // 2,097,152
    const int block = 256;
    const int grid = (n_tiles + block - 1) / block; // 8192 blocks

    subm_conv44_kernel<<<grid, block, 0, stream>>>(x4, W, out4, n_tiles);
}

// Round 2
// 218.476 us; speedup vs baseline: 1.0991x; 1.0991x over previous
//
#include <hip/hip_runtime.h>

// 3x3 'SAME' conv per independent 4x4 tile, masked to nonzero input sites.
// Layout: x flat [N,4,4]; output [N,1,4,4] is flat-identical.
//
// Coalescing fix vs R0: one thread per ROW (float4), not per tile.
// Lane i loads x4[gid] with gid consecutive across the wave -> each
// global_load/store_dwordx4 covers a contiguous 1 KiB. Vertical neighbor
// rows come from intra-wave shuffles (4 lanes per tile, 16 tiles per wave).

__global__ __launch_bounds__(256) void subm_conv44_row_kernel(
    const float4* __restrict__ x4, const float* __restrict__ W,
    float4* __restrict__ out4, int n_rows)
{
    const int gid = blockIdx.x * blockDim.x + threadIdx.x;
    if (gid >= n_rows) return;

    // 3x3 weight, w[ki*3+kj] (HWIO with I=O=1 is flat row-major 3x3).
    float w[9];
#pragma unroll
    for (int i = 0; i < 9; ++i) w[i] = W[i];   // uniform -> scalar/broadcast

    // This thread owns row r of tile (gid>>2).
    const int r = gid & 3;
    const float4 c = x4[gid];                  // coalesced: 16B/lane contiguous

    // Neighbor rows from adjacent lanes (tile = 4 consecutive lanes; a tile
    // never straddles a wave boundary since 64 % 4 == 0).
    float4 u, d;
    u.x = __shfl_up(c.x, 1);  u.y = __shfl_up(c.y, 1);
    u.z = __shfl_up(c.z, 1);  u.w = __shfl_up(c.w, 1);
    d.x = __shfl_down(c.x, 1); d.y = __shfl_down(c.y, 1);
    d.z = __shfl_down(c.z, 1); d.w = __shfl_down(c.w, 1);

    const bool hasU = (r > 0);
    const bool hasD = (r < 3);

    // Zero-padded horizontal windows: idx 0 and 5 are the pad columns.
    float up[6] = {0.f, hasU ? u.x : 0.f, hasU ? u.y : 0.f,
                        hasU ? u.z : 0.f, hasU ? u.w : 0.f, 0.f};
    float mi[6] = {0.f, c.x, c.y, c.z, c.w, 0.f};
    float dn[6] = {0.f, hasD ? d.x : 0.f, hasD ? d.y : 0.f,
                        hasD ? d.z : 0.f, hasD ? d.w : 0.f, 0.f};

    float4 o;
    float* op = &o.x;
#pragma unroll
    for (int j = 0; j < 4; ++j) {
        float acc = 0.0f;
#pragma unroll
        for (int k = 0; k < 3; ++k) {
            acc = fmaf(up[j + k], w[0 * 3 + k], acc);
            acc = fmaf(mi[j + k], w[1 * 3 + k], acc);
            acc = fmaf(dn[j + k], w[2 * 3 + k], acc);
        }
        // Submanifold mask: write only where the input site was nonzero.
        op[j] = (mi[j + 1] != 0.0f) ? acc : 0.0f;
    }

    out4[gid] = o;                             // coalesced store
}

extern "C" void kernel_launch(void* const* d_in, const int* in_sizes, int n_in,
                              void* d_out, int out_size, void* d_ws, size_t ws_size,
                              hipStream_t stream) {
    const float4* x4 = (const float4*)d_in[0];
    const float*  W  = (const float*)d_in[1];
    float4* out4     = (float4*)d_out;

    const int n_rows = in_sizes[0] / 4;            // one float4 row per thread
    const int block = 256;
    const int grid = (n_rows + block - 1) / block; // 32768 blocks

    subm_conv44_row_kernel<<<grid, block, 0, stream>>>(x4, W, out4, n_rows);
}